// Round 1
// baseline (75069.727 us; speedup 1.0000x reference)
//
#include <hip/hip_runtime.h>

typedef unsigned short u16;
typedef unsigned int u32;
typedef unsigned long long u64;
typedef __attribute__((ext_vector_type(8))) short bf16x8;   // 8 bf16 = 4 VGPRs
typedef __attribute__((ext_vector_type(4))) float f32x4;

#define LL 4
#define NN 32
#define SS 2048
#define VV 512
#define DD 512
#define CHUNK 16
#define NCHUNKS (SS / CHUNK)              // 128

#define NCONS 8
#define NBLOCKS 256
#define NPROD (NBLOCKS - NCONS)            // 248
#define FGROUPS 4                          // 128 feats per producer task
#define TASKS (NCHUNKS * NCONS * FGROUPS)  // 4096

// ws layout
#define PRODCNT_OFF 0                      // u32[8][NCHUNKS]
#define CONSDONE_OFF (NCONS * NCHUNKS * 4) // u32[8], 128B-padded
#define RING_OFF 8192
#define SLOT_BYTES ((size_t)NCONS * CHUNK * 8 * 64 * 32)   // 2 MB: [cl][t][w][lane][32B]

// LDS: 128K Wh-tile3 / producer B-stage  +  2 x 16K double-buffered h (swizzled)
#define HB_OFF 131072
#define HB_BYTES 16384
#define LDS_BYTES (HB_OFF + 2 * HB_BYTES)  // 163840 = full 160 KiB

static __device__ __forceinline__ u16 f2bf(float f) {
    u32 x = __float_as_uint(f);
    x += 0x7fffu + ((x >> 16) & 1u);       // round-to-nearest-even
    return (u16)(x >> 16);
}
static __device__ __forceinline__ float bf2f(u32 h) {
    return __uint_as_float((h & 0xffffu) << 16);
}
static __device__ __forceinline__ bf16x8 cvt8(const float* p) {
    f32x4 a = *(const f32x4*)p;
    f32x4 b = *(const f32x4*)(p + 4);
    bf16x8 r;
    r[0] = (short)f2bf(a[0]); r[1] = (short)f2bf(a[1]);
    r[2] = (short)f2bf(a[2]); r[3] = (short)f2bf(a[3]);
    r[4] = (short)f2bf(b[0]); r[5] = (short)f2bf(b[1]);
    r[6] = (short)f2bf(b[2]); r[7] = (short)f2bf(b[3]);
    return r;
}

// LDS-only barrier: order LDS ops across waves WITHOUT draining vmcnt
// (so agent-scope xp loads + global out-stores stay in flight across steps).
// sched_barrier(0) on both sides per guide rule #18 (compiler hoisting hazard).
static __device__ __forceinline__ void lds_barrier() {
    asm volatile("s_waitcnt lgkmcnt(0)" ::: "memory");
    __builtin_amdgcn_sched_barrier(0);
    __builtin_amdgcn_s_barrier();
    __builtin_amdgcn_sched_barrier(0);
}

__global__ __launch_bounds__(512, 2) void rnn_fused(
    const float* __restrict__ x,   // [N][S][V]
    const float* __restrict__ Wx,  // [L][D][V]
    const float* __restrict__ bx,  // [L][D]
    const float* __restrict__ Wh,  // [L][D][D]
    const float* __restrict__ bh,  // [L][D]
    float* __restrict__ out,       // [N][S][D] ++ [L][N][D]
    char* __restrict__ ws, int nslots)
{
    extern __shared__ __align__(16) char lds[];
    const int tid = threadIdx.x;
    const int lane = tid & 63;
    const int w = tid >> 6;                // wave 0..7
    const int col = lane & 15, quad = lane >> 4;
    u32* prod_cnt = (u32*)(ws + PRODCNT_OFF);    // [cl][chunk]
    u32* cons_done = (u32*)(ws + CONSDONE_OFF);  // [cl*32]
    char* ring = ws + RING_OFF;

    if (blockIdx.x < NCONS) {
        // ================= consumer: the sequential scan =================
        const int cl = blockIdx.x;
        const int layer = cl >> 1, nb = cl & 1;
        u16* whlds = (u16*)lds;                   // [w][ks][lane][8 bf16] = 128 KB (tile 3)

        // Wh: tiles 0..2 -> registers (192 regs), tile 3 -> LDS
        bf16x8 whf[48];
#pragma unroll
        for (int tl = 0; tl < 3; ++tl)
#pragma unroll
            for (int ks = 0; ks < 16; ++ks)
                whf[tl * 16 + ks] =
                    cvt8(Wh + ((size_t)layer * DD + (w * 64 + tl * 16 + col)) * DD + 32 * ks + quad * 8);
#pragma unroll
        for (int ks = 0; ks < 16; ++ks) {
            bf16x8 f = cvt8(Wh + ((size_t)layer * DD + (w * 64 + 48 + col)) * DD + 32 * ks + quad * 8);
            *(bf16x8*)(whlds + ((size_t)(w * 16 + ks) * 64 + lane) * 8) = f;
        }
        // zero both h buffers (h[-1] = 0)
        for (int i = tid; i < 2 * HB_BYTES / 4; i += 512) ((u32*)(lds + HB_OFF))[i] = 0u;
        __syncthreads();

        // incremental slot tracking (no per-step % nslots)
        int slot = 0;
        const char* slot_base = ring + (size_t)cl * (CHUNK * 8 * 64 * 32);

        // wait chunk 0, preload xp[0]
        while (__hip_atomic_load(&prod_cnt[cl * NCHUNKS + 0], __ATOMIC_ACQUIRE,
                                 __HIP_MEMORY_SCOPE_AGENT) < FGROUPS)
            __builtin_amdgcn_s_sleep(8);
        u64 xpbuf[2][4];
        {
            const u64* p = (const u64*)(slot_base + ((size_t)w * 64 + lane) * 32);
#pragma unroll
            for (int j = 0; j < 4; ++j)
                xpbuf[0][j] = __hip_atomic_load(p + j, __ATOMIC_RELAXED, __HIP_MEMORY_SCOPE_AGENT);
        }

        const int swz = (col & 7) << 4;
        const int abase = (col << 10) + (quad << 4);   // h[row=col][k = quad*8 + 32*ks]
        float* outp = out + ((size_t)(nb * 16 + quad * 4) * SS) * DD + w * 64 + col;   // layer 3
        float* out2 = out + (size_t)NN * SS * DD
                    + ((size_t)layer * NN + nb * 16 + quad * 4) * DD + w * 64 + col;

        for (int t = 0; t < SS; ++t) {
            const int cur = t & 1;
            // acc init from xp[t] (bias already folded in by producer);
            // this register read forces completion of this wave's chunk-c loads.
            f32x4 acc[4];
#pragma unroll
            for (int tl = 0; tl < 4; ++tl) {
                const u64 v = xpbuf[cur][tl];
                acc[tl][0] = bf2f((u32)v);
                acc[tl][1] = bf2f((u32)(v >> 16));
                acc[tl][2] = bf2f((u32)(v >> 32));
                acc[tl][3] = bf2f((u32)(v >> 48));
            }
            // chunk end: plain barrier (all waves consumed chunk-c xp) then ack,
            // BEFORE polling the next chunk (nslots=1-safe). No vmcnt drain needed:
            // each wave's acc-init already waited on its own loads.
            if ((t & 15) == 15) {
                __builtin_amdgcn_sched_barrier(0);
                __builtin_amdgcn_s_barrier();
                __builtin_amdgcn_sched_barrier(0);
                if (tid == 0)
                    __hip_atomic_store(&cons_done[cl * 32], (u32)((t >> 4) + 1),
                                       __ATOMIC_RELEASE, __HIP_MEMORY_SCOPE_AGENT);
            }
            // prefetch xp[t+1] (in flight across the step barrier — never drained)
            if (t + 1 < SS) {
                if (((t + 1) & 15) == 0) {
                    const int nc = (t + 1) >> 4;
                    while (__hip_atomic_load(&prod_cnt[cl * NCHUNKS + nc], __ATOMIC_ACQUIRE,
                                             __HIP_MEMORY_SCOPE_AGENT) < FGROUPS)
                        __builtin_amdgcn_s_sleep(8);
                    ++slot; if (slot == nslots) slot = 0;
                    slot_base = ring + ((size_t)(slot * NCONS + cl)) * (CHUNK * 8 * 64 * 32);
                }
                const u64* p = (const u64*)(slot_base +
                    (((size_t)((t + 1) & 15) * 8 + w) * 64 + lane) * 32);
#pragma unroll
                for (int j = 0; j < 4; ++j)
                    xpbuf[cur ^ 1][j] =
                        __hip_atomic_load(p + j, __ATOMIC_RELAXED, __HIP_MEMORY_SCOPE_AGENT);
            }
            // recurrent GEMM: A = h[t-1] (LDS buf[t&1], XOR-swizzled), B = Wh (regs + LDS tile 3)
            const char* hrd = lds + HB_OFF + (t & 1) * HB_BYTES;
#pragma unroll
            for (int ks = 0; ks < 16; ++ks) {
                bf16x8 a = *(const bf16x8*)(hrd + ((abase + (ks << 6)) ^ swz));
                acc[0] = __builtin_amdgcn_mfma_f32_16x16x32_bf16(a, whf[ks], acc[0], 0, 0, 0);
                acc[1] = __builtin_amdgcn_mfma_f32_16x16x32_bf16(a, whf[16 + ks], acc[1], 0, 0, 0);
                acc[2] = __builtin_amdgcn_mfma_f32_16x16x32_bf16(a, whf[32 + ks], acc[2], 0, 0, 0);
                bf16x8 b3 = *(const bf16x8*)(whlds + ((size_t)(w * 16 + ks) * 64 + lane) * 8);
                acc[3] = __builtin_amdgcn_mfma_f32_16x16x32_bf16(a, b3, acc[3], 0, 0, 0);
            }
            // sigmoid + h[t] publish into the OTHER buffer + outputs
            char* hwrb = lds + HB_OFF + ((t & 1) ^ 1) * HB_BYTES;
#pragma unroll
            for (int tl = 0; tl < 4; ++tl)
#pragma unroll
                for (int i = 0; i < 4; ++i) {
                    const float s = 1.0f / (1.0f + __expf(-acc[tl][i]));
                    const int row = quad * 4 + i;
                    const int boff = ((row << 10) + ((w * 64 + tl * 16 + col) << 1))
                                   ^ ((row & 7) << 4);
                    *(u16*)(hwrb + boff) = f2bf(s);
                    if (layer == 3) outp[((size_t)i * SS + t) * DD + tl * 16] = s;
                    if (t == SS - 1) out2[(size_t)i * DD + tl * 16] = s;
                }
            // single per-step barrier: LDS-only (h[t] visible); global ops uninterrupted
            lds_barrier();
        }
    } else {
        // ================= producers: xp = Wx x + (bx+bh), chunked =================
        u16* blds = (u16*)lds;   // Wx B-frags: [ct 8][ks 16][lane 64][8 bf16] = 128 KB
        for (int task = blockIdx.x - NCONS; task < TASKS; task += NPROD) {
            const int chunk = task >> 5;
            const int rem = task & 31;
            const int cl = rem >> 2, fg = rem & 3;
            const int layer = cl >> 1, nb = cl & 1;
            const int slot = chunk % nslots;
            // bounded-buffer gate: slot free when consumer finished chunk - nslots
            if (chunk >= nslots && tid == 0) {
                while ((int)__hip_atomic_load(&cons_done[cl * 32], __ATOMIC_ACQUIRE,
                                              __HIP_MEMORY_SCOPE_AGENT) < chunk - nslots + 1)
                    __builtin_amdgcn_s_sleep(16);
            }
            __syncthreads();   // gate known + previous task's LDS reads done
            // stage B = Wx[layer][fg*128 ..+128][512] as bf16 fragments in LDS
            for (int r = 0; r < 16; ++r) {
                const int li = (r * 512 + tid) * 8;
                const int row = li >> 9, k0 = li & 511;
                bf16x8 v = cvt8(Wx + ((size_t)layer * DD + fg * 128 + row) * VV + k0);
                const int ct = row >> 4, fcol = row & 15, ks = k0 >> 5, q = (k0 >> 3) & 3;
                *(bf16x8*)(blds + ((size_t)((ct * 16 + ks) * 64 + q * 16 + fcol)) * 8) = v;
            }
            float bias[8];
#pragma unroll
            for (int ct = 0; ct < 8; ++ct) {
                const int f = layer * DD + fg * 128 + ct * 16 + col;
                bias[ct] = bx[f] + bh[f];
            }
            __syncthreads();
            // compute: wave w -> t_local {2w, 2w+1}; rows = 16 batches
            const int t0 = chunk * CHUNK;
            f32x4 acc[2][8];
#pragma unroll
            for (int rt = 0; rt < 2; ++rt)
#pragma unroll
                for (int ct = 0; ct < 8; ++ct)
                    acc[rt][ct] = f32x4{bias[ct], bias[ct], bias[ct], bias[ct]};
            const float* xr0 = x + ((size_t)(nb * 16 + col) * SS + (t0 + 2 * w)) * VV + quad * 8;
#pragma unroll
            for (int ks = 0; ks < 16; ++ks) {
                bf16x8 a0 = cvt8(xr0 + 32 * ks);
                bf16x8 a1 = cvt8(xr0 + VV + 32 * ks);
#pragma unroll
                for (int ct = 0; ct < 8; ++ct) {
                    bf16x8 b = *(const bf16x8*)(blds + ((size_t)((ct * 16 + ks) * 64 + lane)) * 8);
                    acc[0][ct] = __builtin_amdgcn_mfma_f32_16x16x32_bf16(a0, b, acc[0][ct], 0, 0, 0);
                    acc[1][ct] = __builtin_amdgcn_mfma_f32_16x16x32_bf16(a1, b, acc[1][ct], 0, 0, 0);
                }
            }
            // store in consumer C-frag order: bf16x4 packed u64, agent-scope (L2-bypass)
#pragma unroll
            for (int rt = 0; rt < 2; ++rt) {
                char* base = ring + ((size_t)(slot * NCONS + cl) * CHUNK + (2 * w + rt)) * (8 * 64 * 32);
#pragma unroll
                for (int ct = 0; ct < 8; ++ct) {
                    const int gct = fg * 8 + ct, wc = gct >> 2, tl = gct & 3;
                    const f32x4 a = acc[rt][ct];
                    u64 v = (u64)f2bf(a[0]) | ((u64)f2bf(a[1]) << 16)
                          | ((u64)f2bf(a[2]) << 32) | ((u64)f2bf(a[3]) << 48);
                    __hip_atomic_store((u64*)(base + ((size_t)wc * 64 + lane) * 32 + tl * 8), v,
                                       __ATOMIC_RELAXED, __HIP_MEMORY_SCOPE_AGENT);
                }
            }
            __syncthreads();   // drains all waves' stores (vmcnt0 before s_barrier)
            if (tid == 0)
                __hip_atomic_fetch_add(&prod_cnt[cl * NCHUNKS + chunk], 1u,
                                       __ATOMIC_RELEASE, __HIP_MEMORY_SCOPE_AGENT);
        }
    }
}

extern "C" void kernel_launch(void* const* d_in, const int* in_sizes, int n_in,
                              void* d_out, int out_size, void* d_ws, size_t ws_size,
                              hipStream_t stream) {
    const float* x  = (const float*)d_in[0];
    const float* Wx = (const float*)d_in[1];
    const float* bx = (const float*)d_in[2];
    const float* Wh = (const float*)d_in[3];
    const float* bh = (const float*)d_in[4];
    float* out = (float*)d_out;
    char* ws = (char*)d_ws;

    int nslots = 1;
    if (ws_size > RING_OFF + SLOT_BYTES) {
        size_t n = (ws_size - RING_OFF) / SLOT_BYTES;
        nslots = (int)(n > 8 ? 8 : n);
    }
    hipFuncSetAttribute((const void*)rnn_fused,
                        hipFuncAttributeMaxDynamicSharedMemorySize, LDS_BYTES);
    hipMemsetAsync(ws, 0, RING_OFF, stream);   // zero flags (ws is re-poisoned each call)
    rnn_fused<<<dim3(NBLOCKS), dim3(512), LDS_BYTES, stream>>>(x, Wx, bx, Wh, bh, out, ws, nslots);
}

// Round 2
// 64451.215 us; speedup vs baseline: 1.1648x; 1.1648x over previous
//
#include <hip/hip_runtime.h>

typedef unsigned short u16;
typedef unsigned int u32;
typedef unsigned long long u64;
typedef __attribute__((ext_vector_type(8))) short bf16x8;   // 8 bf16 = 4 VGPRs
typedef __attribute__((ext_vector_type(4))) float f32x4;

#define LL 4
#define NN 32
#define SS 2048
#define VV 512
#define DD 512
#define CHUNK 16
#define NCHUNKS (SS / CHUNK)              // 128

#define NCONS 8
#define NBLOCKS 256
#define NPROD (NBLOCKS - NCONS)            // 248
#define FGROUPS 4                          // 128 feats per producer task
#define TASKS (NCHUNKS * NCONS * FGROUPS)  // 4096

// ws layout
#define PRODCNT_OFF 0                      // u32[8][NCHUNKS]
#define CONSDONE_OFF (NCONS * NCHUNKS * 4) // u32[8], 128B-padded
#define RING_OFF 8192
#define SLOT_BYTES ((size_t)NCONS * CHUNK * 8 * 64 * 32)   // 2 MB: [cl][t][w][lane][32B]

// LDS: 128K Wh-tile3 / producer B-stage  +  2 x 16K double-buffered h (XOR-swizzled).
// Double-buffer requires the 1024-stride layout: PADR=520 x2 would need 164352 B > 160 KiB.
#define HB_OFF 131072
#define HB_BYTES 16384
#define LDS_BYTES (HB_OFF + 2 * HB_BYTES)  // 163840 = full 160 KiB

static __device__ __forceinline__ u16 f2bf(float f) {
    u32 x = __float_as_uint(f);
    x += 0x7fffu + ((x >> 16) & 1u);       // round-to-nearest-even
    return (u16)(x >> 16);
}
static __device__ __forceinline__ float bf2f(u32 h) {
    return __uint_as_float((h & 0xffffu) << 16);
}
static __device__ __forceinline__ bf16x8 cvt8(const float* p) {
    f32x4 a = *(const f32x4*)p;
    f32x4 b = *(const f32x4*)(p + 4);
    bf16x8 r;
    r[0] = (short)f2bf(a[0]); r[1] = (short)f2bf(a[1]);
    r[2] = (short)f2bf(a[2]); r[3] = (short)f2bf(a[3]);
    r[4] = (short)f2bf(b[0]); r[5] = (short)f2bf(b[1]);
    r[6] = (short)f2bf(b[2]); r[7] = (short)f2bf(b[3]);
    return r;
}

__global__ __launch_bounds__(512, 2) void rnn_fused(
    const float* __restrict__ x,   // [N][S][V]
    const float* __restrict__ Wx,  // [L][D][V]
    const float* __restrict__ bx,  // [L][D]
    const float* __restrict__ Wh,  // [L][D][D]
    const float* __restrict__ bh,  // [L][D]
    float* __restrict__ out,       // [N][S][D] ++ [L][N][D]
    char* __restrict__ ws, int nslots)
{
    extern __shared__ __align__(16) char lds[];
    const int tid = threadIdx.x;
    const int lane = tid & 63;
    const int w = tid >> 6;                // wave 0..7
    const int col = lane & 15, quad = lane >> 4;
    u32* prod_cnt = (u32*)(ws + PRODCNT_OFF);    // [cl][chunk]
    u32* cons_done = (u32*)(ws + CONSDONE_OFF);  // [cl*32]
    char* ring = ws + RING_OFF;

    if (blockIdx.x < NCONS) {
        // ================= consumer: the sequential scan =================
        const int cl = blockIdx.x;
        const int layer = cl >> 1, nb = cl & 1;
        u16* whlds = (u16*)lds;                   // [w][ks][lane][8 bf16] = 128 KB (tile 3)

        // Wh: tiles 0..2 -> registers (192 VGPR), tile 3 -> LDS
        bf16x8 whf[48];
#pragma unroll
        for (int tl = 0; tl < 3; ++tl)
#pragma unroll
            for (int ks = 0; ks < 16; ++ks)
                whf[tl * 16 + ks] =
                    cvt8(Wh + ((size_t)layer * DD + (w * 64 + tl * 16 + col)) * DD + 32 * ks + quad * 8);
#pragma unroll
        for (int ks = 0; ks < 16; ++ks) {
            bf16x8 f = cvt8(Wh + ((size_t)layer * DD + (w * 64 + 48 + col)) * DD + 32 * ks + quad * 8);
            *(bf16x8*)(whlds + ((size_t)(w * 16 + ks) * 64 + lane) * 8) = f;
        }
        // zero both h buffers (h[-1] = 0)
        for (int i = tid; i < 2 * HB_BYTES / 4; i += 512) ((u32*)(lds + HB_OFF))[i] = 0u;
        __syncthreads();

        auto xp_addr = [&](int t) -> const u64* {
            const int slot = (t >> 4) % nslots;
            return (const u64*)(ring +
                ((((size_t)(slot * NCONS + cl) * CHUNK + (t & 15)) * 8 + w) * 64 + lane) * 32);
        };
        // wait chunk 0, preload xp[0]
        while (__hip_atomic_load(&prod_cnt[cl * NCHUNKS + 0], __ATOMIC_ACQUIRE,
                                 __HIP_MEMORY_SCOPE_AGENT) < FGROUPS)
            __builtin_amdgcn_s_sleep(8);
        u64 xpbuf[2][4];
        {
            const u64* p = xp_addr(0);
#pragma unroll
            for (int j = 0; j < 4; ++j)
                xpbuf[0][j] = __hip_atomic_load(p + j, __ATOMIC_RELAXED, __HIP_MEMORY_SCOPE_AGENT);
        }

        const int swz = (col & 7) << 4;                // XOR-swizzle: bank spread by read-row
        const int abase = (col << 10) + (quad << 4);   // h[row=col][k = quad*8 + 32*ks]
        float* outp = out + ((size_t)(nb * 16 + quad * 4) * SS) * DD + w * 64 + col;   // layer 3
        float* out2 = out + (size_t)NN * SS * DD
                    + ((size_t)layer * NN + nb * 16 + quad * 4) * DD + w * 64 + col;

        for (int t = 0; t < SS; ++t) {
            const int cur = t & 1;
            // acc init from xp[t] (bias already folded in by producer)
            f32x4 acc[4];
#pragma unroll
            for (int tl = 0; tl < 4; ++tl) {
                const u64 v = xpbuf[cur][tl];
                acc[tl][0] = bf2f((u32)v);
                acc[tl][1] = bf2f((u32)(v >> 16));
                acc[tl][2] = bf2f((u32)(v >> 32));
                acc[tl][3] = bf2f((u32)(v >> 48));
            }
            // chunk boundary: ack consumed chunk BEFORE polling the next (nslots=1-safe).
            // Full __syncthreads: all waves' chunk-c ring loads drained by end of t-1's barrier.
            if ((t & 15) == 15) {
                __syncthreads();
                if (tid == 0)
                    __hip_atomic_store(&cons_done[cl * 32], (u32)((t >> 4) + 1),
                                       __ATOMIC_RELEASE, __HIP_MEMORY_SCOPE_AGENT);
            }
            // prefetch xp[t+1]
            if (t + 1 < SS) {
                if (((t + 1) & 15) == 0) {
                    const int nc = (t + 1) >> 4;
                    while (__hip_atomic_load(&prod_cnt[cl * NCHUNKS + nc], __ATOMIC_ACQUIRE,
                                             __HIP_MEMORY_SCOPE_AGENT) < FGROUPS)
                        __builtin_amdgcn_s_sleep(8);
                }
                const u64* p = xp_addr(t + 1);
#pragma unroll
                for (int j = 0; j < 4; ++j)
                    xpbuf[cur ^ 1][j] =
                        __hip_atomic_load(p + j, __ATOMIC_RELAXED, __HIP_MEMORY_SCOPE_AGENT);
            }
            // recurrent GEMM: A = h[t-1] (LDS buf[t&1], XOR-swizzled), B = Wh (regs + LDS tile 3)
            const char* hrd = lds + HB_OFF + (t & 1) * HB_BYTES;
#pragma unroll
            for (int ks = 0; ks < 16; ++ks) {
                bf16x8 a = *(const bf16x8*)(hrd + ((abase + (ks << 6)) ^ swz));
                acc[0] = __builtin_amdgcn_mfma_f32_16x16x32_bf16(a, whf[ks], acc[0], 0, 0, 0);
                acc[1] = __builtin_amdgcn_mfma_f32_16x16x32_bf16(a, whf[16 + ks], acc[1], 0, 0, 0);
                acc[2] = __builtin_amdgcn_mfma_f32_16x16x32_bf16(a, whf[32 + ks], acc[2], 0, 0, 0);
                bf16x8 b3 = *(const bf16x8*)(whlds + ((size_t)(w * 16 + ks) * 64 + lane) * 8);
                acc[3] = __builtin_amdgcn_mfma_f32_16x16x32_bf16(a, b3, acc[3], 0, 0, 0);
            }
            // NO barrier here: h[t] goes to the OTHER buffer (no WAR vs this step's reads).
            // sigmoid + h[t] publish + outputs
            char* hwrb = lds + HB_OFF + ((t & 1) ^ 1) * HB_BYTES;
#pragma unroll
            for (int tl = 0; tl < 4; ++tl)
#pragma unroll
                for (int i = 0; i < 4; ++i) {
                    const float s = 1.0f / (1.0f + __expf(-acc[tl][i]));
                    const int row = quad * 4 + i;
                    const int boff = ((row << 10) + ((w * 64 + tl * 16 + col) << 1))
                                   ^ ((row & 7) << 4);
                    *(u16*)(hwrb + boff) = f2bf(s);
                    if (layer == 3) outp[((size_t)i * SS + t) * DD + tl * 16] = s;
                    if (t == SS - 1) out2[(size_t)i * DD + tl * 16] = s;
                }
            __syncthreads();   // single per-step barrier: h[t] visible, full drain (round-0 semantics)
        }
    } else {
        // ================= producers: xp = Wx x + (bx+bh), chunked =================
        u16* blds = (u16*)lds;   // Wx B-frags: [ct 8][ks 16][lane 64][8 bf16] = 128 KB
        for (int task = blockIdx.x - NCONS; task < TASKS; task += NPROD) {
            const int chunk = task >> 5;
            const int rem = task & 31;
            const int cl = rem >> 2, fg = rem & 3;
            const int layer = cl >> 1, nb = cl & 1;
            const int slot = chunk % nslots;
            // bounded-buffer gate: slot free when consumer finished chunk - nslots
            if (chunk >= nslots && tid == 0) {
                while ((int)__hip_atomic_load(&cons_done[cl * 32], __ATOMIC_ACQUIRE,
                                              __HIP_MEMORY_SCOPE_AGENT) < chunk - nslots + 1)
                    __builtin_amdgcn_s_sleep(16);
            }
            __syncthreads();   // gate known + previous task's LDS reads done
            // stage B = Wx[layer][fg*128 ..+128][512] as bf16 fragments in LDS
            for (int r = 0; r < 16; ++r) {
                const int li = (r * 512 + tid) * 8;
                const int row = li >> 9, k0 = li & 511;
                bf16x8 v = cvt8(Wx + ((size_t)layer * DD + fg * 128 + row) * VV + k0);
                const int ct = row >> 4, fcol = row & 15, ks = k0 >> 5, q = (k0 >> 3) & 3;
                *(bf16x8*)(blds + ((size_t)((ct * 16 + ks) * 64 + q * 16 + fcol)) * 8) = v;
            }
            float bias[8];
#pragma unroll
            for (int ct = 0; ct < 8; ++ct) {
                const int f = layer * DD + fg * 128 + ct * 16 + col;
                bias[ct] = bx[f] + bh[f];
            }
            __syncthreads();
            // compute: wave w -> t_local {2w, 2w+1}; rows = 16 batches
            const int t0 = chunk * CHUNK;
            f32x4 acc[2][8];
#pragma unroll
            for (int rt = 0; rt < 2; ++rt)
#pragma unroll
                for (int ct = 0; ct < 8; ++ct)
                    acc[rt][ct] = f32x4{bias[ct], bias[ct], bias[ct], bias[ct]};
            const float* xr0 = x + ((size_t)(nb * 16 + col) * SS + (t0 + 2 * w)) * VV + quad * 8;
#pragma unroll
            for (int ks = 0; ks < 16; ++ks) {
                bf16x8 a0 = cvt8(xr0 + 32 * ks);
                bf16x8 a1 = cvt8(xr0 + VV + 32 * ks);
#pragma unroll
                for (int ct = 0; ct < 8; ++ct) {
                    bf16x8 b = *(const bf16x8*)(blds + ((size_t)((ct * 16 + ks) * 64 + lane)) * 8);
                    acc[0][ct] = __builtin_amdgcn_mfma_f32_16x16x32_bf16(a0, b, acc[0][ct], 0, 0, 0);
                    acc[1][ct] = __builtin_amdgcn_mfma_f32_16x16x32_bf16(a1, b, acc[1][ct], 0, 0, 0);
                }
            }
            // store in consumer C-frag order: bf16x4 packed u64, agent-scope (L2-bypass)
#pragma unroll
            for (int rt = 0; rt < 2; ++rt) {
                char* base = ring + ((size_t)(slot * NCONS + cl) * CHUNK + (2 * w + rt)) * (8 * 64 * 32);
#pragma unroll
                for (int ct = 0; ct < 8; ++ct) {
                    const int gct = fg * 8 + ct, wc = gct >> 2, tl = gct & 3;
                    const f32x4 a = acc[rt][ct];
                    u64 v = (u64)f2bf(a[0]) | ((u64)f2bf(a[1]) << 16)
                          | ((u64)f2bf(a[2]) << 32) | ((u64)f2bf(a[3]) << 48);
                    __hip_atomic_store((u64*)(base + ((size_t)wc * 64 + lane) * 32 + tl * 8), v,
                                       __ATOMIC_RELAXED, __HIP_MEMORY_SCOPE_AGENT);
                }
            }
            __syncthreads();   // drains all waves' stores (vmcnt0 before s_barrier)
            if (tid == 0)
                __hip_atomic_fetch_add(&prod_cnt[cl * NCHUNKS + chunk], 1u,
                                       __ATOMIC_RELEASE, __HIP_MEMORY_SCOPE_AGENT);
        }
    }
}

extern "C" void kernel_launch(void* const* d_in, const int* in_sizes, int n_in,
                              void* d_out, int out_size, void* d_ws, size_t ws_size,
                              hipStream_t stream) {
    const float* x  = (const float*)d_in[0];
    const float* Wx = (const float*)d_in[1];
    const float* bx = (const float*)d_in[2];
    const float* Wh = (const float*)d_in[3];
    const float* bh = (const float*)d_in[4];
    float* out = (float*)d_out;
    char* ws = (char*)d_ws;

    int nslots = 1;
    if (ws_size > RING_OFF + SLOT_BYTES) {
        size_t n = (ws_size - RING_OFF) / SLOT_BYTES;
        nslots = (int)(n > 8 ? 8 : n);
    }
    hipFuncSetAttribute((const void*)rnn_fused,
                        hipFuncAttributeMaxDynamicSharedMemorySize, LDS_BYTES);
    hipMemsetAsync(ws, 0, RING_OFF, stream);   // zero flags (ws is re-poisoned each call)
    rnn_fused<<<dim3(NBLOCKS), dim3(512), LDS_BYTES, stream>>>(x, Wx, bx, Wh, bh, out, ws, nslots);
}

// Round 3
// 20907.372 us; speedup vs baseline: 3.5906x; 3.0827x over previous
//
#include <hip/hip_runtime.h>

typedef unsigned short u16;
typedef unsigned int u32;
typedef unsigned long long u64;
typedef __attribute__((ext_vector_type(8))) short bf16x8;   // 8 bf16 = 4 VGPRs
typedef __attribute__((ext_vector_type(4))) float f32x4;

#define LL 4
#define NN 32
#define SS 2048
#define VV 512
#define DD 512
#define CHUNK 16
#define NCHUNKS (SS / CHUNK)              // 128
#define PADR 520                           // h row stride (u16): 16B-aligned, odd*16B

#define NCONS 8
#define NBLOCKS 256
#define FGROUPS 4                          // 128 feats per producer combo
#define NCOMBOS 32                         // 8 cl x 4 fg
#define CRES 7                             // chunk residues per combo
#define NPROD_ACTIVE (NCOMBOS * CRES)      // 224 persistent producer blocks

// ws layout
#define PRODCNT_OFF 0                      // u32[8][NCHUNKS]
#define CONSDONE_OFF (NCONS * NCHUNKS * 4) // u32[8], 128B-padded
#define RING_OFF 8192
#define SLOT_BYTES ((size_t)NCONS * CHUNK * 8 * 64 * 32)   // 2 MB: [cl][t][w][lane][32B]

#define LDS_BYTES (131072 + 16 * PADR * 2) // 128K Wh-tile3 / B-stage  +  16.6K h

static __device__ __forceinline__ u16 f2bf(float f) {
    u32 x = __float_as_uint(f);
    x += 0x7fffu + ((x >> 16) & 1u);       // round-to-nearest-even
    return (u16)(x >> 16);
}
static __device__ __forceinline__ float bf2f(u32 h) {
    return __uint_as_float((h & 0xffffu) << 16);
}
static __device__ __forceinline__ bf16x8 cvt8(const float* p) {
    f32x4 a = *(const f32x4*)p;
    f32x4 b = *(const f32x4*)(p + 4);
    bf16x8 r;
    r[0] = (short)f2bf(a[0]); r[1] = (short)f2bf(a[1]);
    r[2] = (short)f2bf(a[2]); r[3] = (short)f2bf(a[3]);
    r[4] = (short)f2bf(b[0]); r[5] = (short)f2bf(b[1]);
    r[6] = (short)f2bf(b[2]); r[7] = (short)f2bf(b[3]);
    return r;
}

__global__ __launch_bounds__(512, 2) void rnn_fused(
    const float* __restrict__ x,   // [N][S][V]
    const float* __restrict__ Wx,  // [L][D][V]
    const float* __restrict__ bx,  // [L][D]
    const float* __restrict__ Wh,  // [L][D][D]
    const float* __restrict__ bh,  // [L][D]
    float* __restrict__ out,       // [N][S][D] ++ [L][N][D]
    char* __restrict__ ws, int nslots)
{
    extern __shared__ __align__(16) char lds[];
    const int tid = threadIdx.x;
    const int lane = tid & 63;
    const int w = tid >> 6;                // wave 0..7
    const int col = lane & 15, quad = lane >> 4;
    u32* prod_cnt = (u32*)(ws + PRODCNT_OFF);    // [cl][chunk]
    u32* cons_done = (u32*)(ws + CONSDONE_OFF);  // [cl*32]
    char* ring = ws + RING_OFF;

    if (blockIdx.x < NCONS) {
        // ========== consumer: the sequential scan (round-0-proven structure) ==========
        const int cl = blockIdx.x;
        const int layer = cl >> 1, nb = cl & 1;
        u16* whlds = (u16*)lds;                   // [w][ks][lane][8 bf16] = 128 KB (tile 3)
        u16* hb = (u16*)(lds + 131072);           // [16][PADR]

        // Wh: tiles 0..2 -> registers (192 VGPR), tile 3 -> LDS
        bf16x8 whf[48];
#pragma unroll
        for (int tl = 0; tl < 3; ++tl)
#pragma unroll
            for (int ks = 0; ks < 16; ++ks)
                whf[tl * 16 + ks] =
                    cvt8(Wh + ((size_t)layer * DD + (w * 64 + tl * 16 + col)) * DD + 32 * ks + quad * 8);
#pragma unroll
        for (int ks = 0; ks < 16; ++ks) {
            bf16x8 f = cvt8(Wh + ((size_t)layer * DD + (w * 64 + 48 + col)) * DD + 32 * ks + quad * 8);
            *(bf16x8*)(whlds + ((size_t)(w * 16 + ks) * 64 + lane) * 8) = f;
        }
        for (int i = tid; i < 16 * PADR; i += 512) hb[i] = 0;   // h[-1] = 0
        __syncthreads();

        auto xp_addr = [&](int t) -> const u64* {
            const int slot = (t >> 4) % nslots;
            return (const u64*)(ring +
                ((((size_t)(slot * NCONS + cl) * CHUNK + (t & 15)) * 8 + w) * 64 + lane) * 32);
        };
        // wait chunk 0, preload xp[0]
        while (__hip_atomic_load(&prod_cnt[cl * NCHUNKS + 0], __ATOMIC_ACQUIRE,
                                 __HIP_MEMORY_SCOPE_AGENT) < FGROUPS)
            __builtin_amdgcn_s_sleep(8);
        u64 xpbuf[2][4];
        {
            const u64* p = xp_addr(0);
#pragma unroll
            for (int j = 0; j < 4; ++j)
                xpbuf[0][j] = __hip_atomic_load(p + j, __ATOMIC_RELAXED, __HIP_MEMORY_SCOPE_AGENT);
        }

        const u16* hrd = hb + col * PADR + quad * 8;
        u16* hwr = hb + (quad * 4) * PADR + w * 64 + col;
        float* outp = out + ((size_t)(nb * 16 + quad * 4) * SS) * DD + w * 64 + col;   // layer 3
        float* out2 = out + (size_t)NN * SS * DD
                    + ((size_t)layer * NN + nb * 16 + quad * 4) * DD + w * 64 + col;

        for (int t = 0; t < SS; ++t) {
            const int cur = t & 1;
            // acc init from xp[t] (bias already folded in by producer)
            f32x4 acc[4];
#pragma unroll
            for (int tl = 0; tl < 4; ++tl) {
                const u64 v = xpbuf[cur][tl];
                acc[tl][0] = bf2f((u32)v);
                acc[tl][1] = bf2f((u32)(v >> 16));
                acc[tl][2] = bf2f((u32)(v >> 32));
                acc[tl][3] = bf2f((u32)(v >> 48));
            }
            // chunk boundary: ack chunk c as consumed. No extra barrier needed:
            // step t-1's closing __syncthreads already rendezvoused all waves AFTER
            // each drained its chunk-c prefetch loads (vmcnt(0) precedes s_barrier),
            // so all of chunk c is in registers. Ack precedes the t+1 poll (nslots=1-safe).
            if ((t & 15) == 15) {
                if (tid == 0)
                    __hip_atomic_store(&cons_done[cl * 32], (u32)((t >> 4) + 1),
                                       __ATOMIC_RELEASE, __HIP_MEMORY_SCOPE_AGENT);
            }
            // prefetch xp[t+1]
            if (t + 1 < SS) {
                if (((t + 1) & 15) == 0) {
                    const int nc = (t + 1) >> 4;
                    while (__hip_atomic_load(&prod_cnt[cl * NCHUNKS + nc], __ATOMIC_ACQUIRE,
                                             __HIP_MEMORY_SCOPE_AGENT) < FGROUPS)
                        __builtin_amdgcn_s_sleep(8);
                }
                const u64* p = xp_addr(t + 1);
#pragma unroll
                for (int j = 0; j < 4; ++j)
                    xpbuf[cur ^ 1][j] =
                        __hip_atomic_load(p + j, __ATOMIC_RELAXED, __HIP_MEMORY_SCOPE_AGENT);
            }
            // recurrent GEMM: A = h[t-1] (LDS), B = Wh (regs + LDS tile 3)
#pragma unroll
            for (int ks = 0; ks < 16; ++ks) {
                bf16x8 a = *(const bf16x8*)(hrd + 32 * ks);
                acc[0] = __builtin_amdgcn_mfma_f32_16x16x32_bf16(a, whf[ks], acc[0], 0, 0, 0);
                acc[1] = __builtin_amdgcn_mfma_f32_16x16x32_bf16(a, whf[16 + ks], acc[1], 0, 0, 0);
                acc[2] = __builtin_amdgcn_mfma_f32_16x16x32_bf16(a, whf[32 + ks], acc[2], 0, 0, 0);
                bf16x8 b3 = *(const bf16x8*)(whlds + ((size_t)(w * 16 + ks) * 64 + lane) * 8);
                acc[3] = __builtin_amdgcn_mfma_f32_16x16x32_bf16(a, b3, acc[3], 0, 0, 0);
            }
            __syncthreads();   // barrier 1: all h[t-1] reads done
            // sigmoid + h[t] publish + outputs
#pragma unroll
            for (int tl = 0; tl < 4; ++tl)
#pragma unroll
                for (int i = 0; i < 4; ++i) {
                    const float s = 1.0f / (1.0f + __expf(-acc[tl][i]));
                    hwr[i * PADR + tl * 16] = f2bf(s);
                    if (layer == 3) outp[((size_t)i * SS + t) * DD + tl * 16] = s;
                    if (t == SS - 1) out2[(size_t)i * DD + tl * 16] = s;
                }
            __syncthreads();   // barrier 2: h[t] visible
        }
    } else {
        // ========== persistent producers: xp = Wx x + (bx+bh) ==========
        // Block q owns combo (cl,fg) = q%32 forever; stages its Wx slice into LDS ONCE;
        // handles chunks  q/32, q/32+7, ...  Compute runs BEFORE the slot gate (x and
        // the staged Wx are never gated), so the exposed per-chunk latency after the
        // consumer's ack is just wake + ring stores + ack.
        const int q = blockIdx.x - NCONS;
        if (q >= NPROD_ACTIVE) return;
        const int combo = q & 31;
        const int cl = combo >> 2, fg = combo & 3;
        const int layer = cl >> 1, nb = cl & 1;
        u16* blds = (u16*)lds;   // Wx B-frags: [ct 8][ks 16][lane 64][8 bf16] = 128 KB

        // stage B = Wx[layer][fg*128 ..+128][512] as bf16 fragments in LDS (once)
        for (int r = 0; r < 16; ++r) {
            const int li = (r * 512 + tid) * 8;
            const int row = li >> 9, k0 = li & 511;
            bf16x8 v = cvt8(Wx + ((size_t)layer * DD + fg * 128 + row) * VV + k0);
            const int ct = row >> 4, fcol = row & 15, ks = k0 >> 5, qd = (k0 >> 3) & 3;
            *(bf16x8*)(blds + ((size_t)((ct * 16 + ks) * 64 + qd * 16 + fcol)) * 8) = v;
        }
        float bias[8];
#pragma unroll
        for (int ct = 0; ct < 8; ++ct) {
            const int f = layer * DD + fg * 128 + ct * 16 + col;
            bias[ct] = bx[f] + bh[f];
        }
        __syncthreads();

        for (int chunk = q >> 5; chunk < NCHUNKS; chunk += CRES) {
            // ---- compute first (ungated) ----
            const int t0 = chunk * CHUNK;
            f32x4 acc[2][8];
#pragma unroll
            for (int rt = 0; rt < 2; ++rt)
#pragma unroll
                for (int ct = 0; ct < 8; ++ct)
                    acc[rt][ct] = f32x4{bias[ct], bias[ct], bias[ct], bias[ct]};
            const float* xr0 = x + ((size_t)(nb * 16 + col) * SS + (t0 + 2 * w)) * VV + quad * 8;
#pragma unroll
            for (int ks = 0; ks < 16; ++ks) {
                bf16x8 a0 = cvt8(xr0 + 32 * ks);
                bf16x8 a1 = cvt8(xr0 + VV + 32 * ks);
#pragma unroll
                for (int ct = 0; ct < 8; ++ct) {
                    bf16x8 b = *(const bf16x8*)(blds + ((size_t)((ct * 16 + ks) * 64 + lane)) * 8);
                    acc[0][ct] = __builtin_amdgcn_mfma_f32_16x16x32_bf16(a0, b, acc[0][ct], 0, 0, 0);
                    acc[1][ct] = __builtin_amdgcn_mfma_f32_16x16x32_bf16(a1, b, acc[1][ct], 0, 0, 0);
                }
            }
            // ---- bounded-buffer gate: slot free when consumer finished chunk - nslots ----
            const int slot = chunk % nslots;
            if (chunk >= nslots && tid == 0) {
                while ((int)__hip_atomic_load(&cons_done[cl * 32], __ATOMIC_ACQUIRE,
                                              __HIP_MEMORY_SCOPE_AGENT) < chunk - nslots + 1)
                    __builtin_amdgcn_s_sleep(16);
            }
            __syncthreads();   // gate known to all waves
            // ---- store in consumer C-frag order: bf16x4 packed u64, agent-scope ----
#pragma unroll
            for (int rt = 0; rt < 2; ++rt) {
                char* base = ring + ((size_t)(slot * NCONS + cl) * CHUNK + (2 * w + rt)) * (8 * 64 * 32);
#pragma unroll
                for (int ct = 0; ct < 8; ++ct) {
                    const int gct = fg * 8 + ct, wc = gct >> 2, tl = gct & 3;
                    const f32x4 a = acc[rt][ct];
                    u64 v = (u64)f2bf(a[0]) | ((u64)f2bf(a[1]) << 16)
                          | ((u64)f2bf(a[2]) << 32) | ((u64)f2bf(a[3]) << 48);
                    __hip_atomic_store((u64*)(base + ((size_t)wc * 64 + lane) * 32 + tl * 8), v,
                                       __ATOMIC_RELAXED, __HIP_MEMORY_SCOPE_AGENT);
                }
            }
            __syncthreads();   // drains all waves' stores (vmcnt0 before s_barrier)
            if (tid == 0)
                __hip_atomic_fetch_add(&prod_cnt[cl * NCHUNKS + chunk], 1u,
                                       __ATOMIC_RELEASE, __HIP_MEMORY_SCOPE_AGENT);
        }
    }
}

extern "C" void kernel_launch(void* const* d_in, const int* in_sizes, int n_in,
                              void* d_out, int out_size, void* d_ws, size_t ws_size,
                              hipStream_t stream) {
    const float* x  = (const float*)d_in[0];
    const float* Wx = (const float*)d_in[1];
    const float* bx = (const float*)d_in[2];
    const float* Wh = (const float*)d_in[3];
    const float* bh = (const float*)d_in[4];
    float* out = (float*)d_out;
    char* ws = (char*)d_ws;

    int nslots = 1;
    if (ws_size > RING_OFF + SLOT_BYTES) {
        size_t n = (ws_size - RING_OFF) / SLOT_BYTES;
        nslots = (int)(n > 8 ? 8 : n);
    }
    hipFuncSetAttribute((const void*)rnn_fused,
                        hipFuncAttributeMaxDynamicSharedMemorySize, LDS_BYTES);
    hipMemsetAsync(ws, 0, RING_OFF, stream);   // zero flags (ws is re-poisoned each call)
    rnn_fused<<<dim3(NBLOCKS), dim3(512), LDS_BYTES, stream>>>(x, Wx, bx, Wh, bh, out, ws, nslots);
}